// Round 5
// baseline (147.062 us; speedup 1.0000x reference)
//
#include <hip/hip_runtime.h>
#include <hip/hip_fp16.h>
#include <math.h>

#define K_NB  32
#define C_IN  64
#define C_OUT 128
#define KPAD  68     // pooled row: 64 x-ch + 3 rel-xyz + 1 zero pad

__device__ __forceinline__ float2 u2f2(unsigned u) {
    __half2 h = *reinterpret_cast<__half2*>(&u);
    return __half22float2(h);
}

// ---------------------------------------------------------------------------
// zero n floats
// ---------------------------------------------------------------------------
__global__ __launch_bounds__(256) void sa_zero(float* __restrict__ g, int n)
{
    for (int i = threadIdx.x; i < n; i += 256) g[i] = 0.f;
}

// ---------------------------------------------------------------------------
// x (f32) -> fp16 copy in ws
// ---------------------------------------------------------------------------
__global__ __launch_bounds__(256) void sa_cvt(
    const float4* __restrict__ x4, uint2* __restrict__ xh, int n4)
{
    for (int i = blockIdx.x * blockDim.x + threadIdx.x; i < n4;
         i += gridDim.x * blockDim.x) {
        float4 v = x4[i];
        __half2 lo = __floats2half2_rn(v.x, v.y);
        __half2 hi = __floats2half2_rn(v.z, v.w);
        union { __half2 h; unsigned u; } a, b;
        a.h = lo; b.h = hi;
        xh[i] = make_uint2(a.u, b.u);
    }
}

// ---------------------------------------------------------------------------
// pooled[m, 0..67] = [ max_k x[knn], max_k p[knn] - p[idx], 0 ] ; n_p = p[idx]
// One wave per point; gather via dwordx4 over fp16 rows (8 rows / instruction).
// pooled written into the h region of d_out (cols 0..67 of each 128-col row).
// ---------------------------------------------------------------------------
__global__ __launch_bounds__(256) void sa_pool_h(
    const float* __restrict__ p, const uint4* __restrict__ xh4,
    const int* __restrict__ idx, const int* __restrict__ knn,
    float* __restrict__ np_out, float* __restrict__ pooled)
{
    const int lane = threadIdx.x & 63;
    const int m    = blockIdx.x * 4 + (threadIdx.x >> 6);

    int kidx = 0;
    if (lane < K_NB) kidx = knn[m * K_NB + lane];

    float mx[8];
    #pragma unroll
    for (int j = 0; j < 8; ++j) mx[j] = -INFINITY;

    const int sub = lane & 7;            // 16B slice within the 128B row
    #pragma unroll
    for (int i = 0; i < 4; ++i) {
        int nb = __shfl(kidx, i * 8 + (lane >> 3));   // 8 rows in flight per inst
        uint4 u = xh4[(size_t)nb * 8 + sub];
        float2 f0 = u2f2(u.x), f1 = u2f2(u.y), f2 = u2f2(u.z), f3 = u2f2(u.w);
        mx[0] = fmaxf(mx[0], f0.x); mx[1] = fmaxf(mx[1], f0.y);
        mx[2] = fmaxf(mx[2], f1.x); mx[3] = fmaxf(mx[3], f1.y);
        mx[4] = fmaxf(mx[4], f2.x); mx[5] = fmaxf(mx[5], f2.y);
        mx[6] = fmaxf(mx[6], f3.x); mx[7] = fmaxf(mx[7], f3.y);
    }
    // merge the 8 row-groups (lane bits 3,4,5)
    #pragma unroll
    for (int off = 8; off <= 32; off <<= 1)
        #pragma unroll
        for (int j = 0; j < 8; ++j)
            mx[j] = fmaxf(mx[j], __shfl_xor(mx[j], off));

    // xyz max-pool (fp32 p, L2-resident)
    float px = -INFINITY, py = -INFINITY, pz = -INFINITY;
    if (lane < K_NB) {
        const float* pp = p + (size_t)kidx * 3;
        px = pp[0]; py = pp[1]; pz = pp[2];
    }
    #pragma unroll
    for (int off = 32; off >= 1; off >>= 1) {
        px = fmaxf(px, __shfl_xor(px, off));
        py = fmaxf(py, __shfl_xor(py, off));
        pz = fmaxf(pz, __shfl_xor(pz, off));
    }

    const int s = idx[m];
    const float npx = p[(size_t)s*3+0];
    const float npy = p[(size_t)s*3+1];
    const float npz = p[(size_t)s*3+2];
    if (lane < 3) np_out[(size_t)m*3 + lane] = (lane == 0) ? npx : (lane == 1 ? npy : npz);

    float* row = pooled + (size_t)m * C_OUT;
    if (lane < 8) {
        *(float4*)(row + lane*8)     = make_float4(mx[0], mx[1], mx[2], mx[3]);
        *(float4*)(row + lane*8 + 4) = make_float4(mx[4], mx[5], mx[6], mx[7]);
    } else if (lane == 8) {
        *(float4*)(row + C_IN) = make_float4(px - npx, py - npy, pz - npz, 0.f);
    }
}

// f32 fallback (only if ws can't hold the fp16 x copy)
__global__ __launch_bounds__(256) void sa_pool_f(
    const float* __restrict__ p, const float* __restrict__ x,
    const int* __restrict__ idx, const int* __restrict__ knn,
    float* __restrict__ np_out, float* __restrict__ pooled)
{
    const int lane = threadIdx.x & 63;
    const int m    = blockIdx.x * 4 + (threadIdx.x >> 6);
    int kidx = 0;
    if (lane < K_NB) kidx = knn[m * K_NB + lane];
    float xmax = -INFINITY;
    #pragma unroll
    for (int k = 0; k < K_NB; ++k) {
        int nb = __shfl(kidx, k);
        xmax = fmaxf(xmax, x[(size_t)nb * C_IN + lane]);
    }
    float px = -INFINITY, py = -INFINITY, pz = -INFINITY;
    if (lane < K_NB) {
        const float* pp = p + (size_t)kidx * 3;
        px = pp[0]; py = pp[1]; pz = pp[2];
    }
    #pragma unroll
    for (int off = 32; off >= 1; off >>= 1) {
        px = fmaxf(px, __shfl_xor(px, off));
        py = fmaxf(py, __shfl_xor(py, off));
        pz = fmaxf(pz, __shfl_xor(pz, off));
    }
    const int s = idx[m];
    const float npx = p[(size_t)s*3], npy = p[(size_t)s*3+1], npz = p[(size_t)s*3+2];
    if (lane < 3) np_out[(size_t)m*3 + lane] = (lane == 0) ? npx : (lane == 1 ? npy : npz);
    float* row = pooled + (size_t)m * C_OUT;
    row[lane] = xmax;
    if (lane == 0) *(float4*)(row + C_IN) = make_float4(px-npx, py-npy, pz-npz, 0.f);
}

// ---------------------------------------------------------------------------
// h[m,:] = pooled[m,:] @ Wp + b  with fused BN partial stats.
// 64 rows x 128 cols per block, 256 threads, 8 rows x 4 cols per thread.
// BN partials go to gsum replica (blockIdx & rep_mask) to kill same-line
// atomic serialization (contention 1024 -> 1024/REP per cache line).
// ---------------------------------------------------------------------------
__global__ __launch_bounds__(256) void sa_gemm(
    const float* __restrict__ W, const float* __restrict__ bias,
    float* __restrict__ h, float* __restrict__ gsum, unsigned rep_mask)
{
    __shared__ float Wl[KPAD * C_OUT];   // 34816 B
    __shared__ float PlT[KPAD][KPAD];    // 18496 B
    const int t  = threadIdx.x;
    const int m0 = blockIdx.x * 64;

    // stage W permuted: pooled col j<64 -> W row 3+j; cols 64..66 -> rows 0..2
    for (int v = t; v < KPAD * C_OUT; v += 256) {
        const int j = v >> 7, col = v & 127;
        float w = 0.f;
        if (j < C_IN)          w = W[(size_t)(3 + j) * C_OUT + col];
        else if (j < C_IN + 3) w = W[(size_t)(j - C_IN) * C_OUT + col];
        Wl[v] = w;
    }
    // stage pooled transposed
    const float4* h4 = (const float4*)(h + (size_t)m0 * C_OUT);
    for (int v = t; v < 64 * 17; v += 256) {
        const int r = v / 17, q = v - r * 17;
        float4 f = h4[r * 32 + q];
        PlT[4*q+0][r] = f.x;
        PlT[4*q+1][r] = f.y;
        PlT[4*q+2][r] = f.z;
        PlT[4*q+3][r] = f.w;
    }
    __syncthreads();

    const int c0 = (t & 31) * 4;
    const int r0 = (t >> 5) * 8;
    const float4 bv = *(const float4*)&bias[c0];
    float acc[8][4];
    #pragma unroll
    for (int i = 0; i < 8; ++i) {
        acc[i][0] = bv.x; acc[i][1] = bv.y; acc[i][2] = bv.z; acc[i][3] = bv.w;
    }
    for (int c = 0; c < 67; ++c) {
        const float4 w4 = *(const float4*)&Wl[c * C_OUT + c0];
        const float4 a0 = *(const float4*)&PlT[c][r0];
        const float4 a1 = *(const float4*)&PlT[c][r0 + 4];
        const float a[8] = {a0.x, a0.y, a0.z, a0.w, a1.x, a1.y, a1.z, a1.w};
        #pragma unroll
        for (int i = 0; i < 8; ++i) {
            acc[i][0] = fmaf(a[i], w4.x, acc[i][0]);
            acc[i][1] = fmaf(a[i], w4.y, acc[i][1]);
            acc[i][2] = fmaf(a[i], w4.z, acc[i][2]);
            acc[i][3] = fmaf(a[i], w4.w, acc[i][3]);
        }
    }

    float s[4] = {0,0,0,0}, q[4] = {0,0,0,0};
    #pragma unroll
    for (int i = 0; i < 8; ++i) {
        *(float4*)&h[(size_t)(m0 + r0 + i) * C_OUT + c0] =
            make_float4(acc[i][0], acc[i][1], acc[i][2], acc[i][3]);
        #pragma unroll
        for (int j = 0; j < 4; ++j) {
            s[j] += acc[i][j];
            q[j]  = fmaf(acc[i][j], acc[i][j], q[j]);
        }
    }

    __syncthreads();                       // PlT reads done; reuse for reduction
    float* reds = &PlT[0][0];              // 8*128 floats
    float* redq = reds + 8 * C_OUT;        // 8*128 floats
    #pragma unroll
    for (int j = 0; j < 4; ++j) {
        reds[(t >> 5) * C_OUT + c0 + j] = s[j];
        redq[(t >> 5) * C_OUT + c0 + j] = q[j];
    }
    __syncthreads();
    if (t < C_OUT) {
        float ss = 0.f, qq = 0.f;
        #pragma unroll
        for (int i = 0; i < 8; ++i) { ss += reds[i * C_OUT + t]; qq += redq[i * C_OUT + t]; }
        float* g = gsum + (size_t)(blockIdx.x & rep_mask) * 2 * C_OUT;
        atomicAdd(&g[t],         ss);
        atomicAdd(&g[C_OUT + t], qq);
    }
}

// ---------------------------------------------------------------------------
// sum replicas -> per-channel scale/shift; writes n_o
// ---------------------------------------------------------------------------
__global__ __launch_bounds__(128) void sa_finalize(
    const float* __restrict__ gsum, const float* __restrict__ gamma,
    const float* __restrict__ beta, float* __restrict__ ss,
    float* __restrict__ no_out, int M, int rep)
{
    const int j = threadIdx.x;
    float s = 0.f, s2 = 0.f;
    for (int r = 0; r < rep; ++r) {
        s  += gsum[(size_t)r * 2 * C_OUT + j];
        s2 += gsum[(size_t)r * 2 * C_OUT + C_OUT + j];
    }
    const float inv_m = 1.0f / (float)M;
    const float mean = s * inv_m;
    const float var  = fmaf(-mean, mean, s2 * inv_m);
    const float sc   = gamma[j] * rsqrtf(var + 1e-5f);
    ss[j]         = sc;
    ss[C_OUT + j] = fmaf(-mean, sc, beta[j]);
    if (j == 0) no_out[0] = (float)M;
}

// ---------------------------------------------------------------------------
// in-place affine + ReLU over h (float4)
// ---------------------------------------------------------------------------
__global__ __launch_bounds__(256) void sa_bnrelu(
    float* __restrict__ h, const float* __restrict__ ss, int M)
{
    __shared__ float sc[C_OUT], sh[C_OUT];
    if (threadIdx.x < C_OUT) {
        sc[threadIdx.x] = ss[threadIdx.x];
        sh[threadIdx.x] = ss[C_OUT + threadIdx.x];
    }
    __syncthreads();
    const size_t total4 = (size_t)M * C_OUT / 4;
    float4* h4 = (float4*)h;
    for (size_t i = (size_t)blockIdx.x * blockDim.x + threadIdx.x;
         i < total4; i += (size_t)gridDim.x * blockDim.x) {
        float4 v = h4[i];
        const int c = (int)((i * 4) & (C_OUT - 1));
        v.x = fmaxf(fmaf(v.x, sc[c+0], sh[c+0]), 0.f);
        v.y = fmaxf(fmaf(v.y, sc[c+1], sh[c+1]), 0.f);
        v.z = fmaxf(fmaf(v.z, sc[c+2], sh[c+2]), 0.f);
        v.w = fmaxf(fmaf(v.w, sc[c+3], sh[c+3]), 0.f);
        h4[i] = v;
    }
}

extern "C" void kernel_launch(void* const* d_in, const int* in_sizes, int n_in,
                              void* d_out, int out_size, void* d_ws, size_t ws_size,
                              hipStream_t stream)
{
    const float* p     = (const float*)d_in[0];
    const float* x     = (const float*)d_in[1];
    // d_in[2] = o (unused)
    const int*   idx   = (const int*)d_in[3];
    const int*   knn   = (const int*)d_in[4];
    const float* W     = (const float*)d_in[5];
    const float* bias  = (const float*)d_in[6];
    const float* gamma = (const float*)d_in[7];
    const float* beta  = (const float*)d_in[8];

    const int N = in_sizes[1] / C_IN;  // 262144
    const int M = in_sizes[3];         // 65536

    float* out    = (float*)d_out;
    float* np_out = out;                                     // [M,3]
    float* h      = out + (size_t)M * 3;                     // [M,128]
    float* no_out = out + (size_t)M * 3 + (size_t)M * C_OUT; // [1]

    const size_t xh_bytes  = (size_t)N * C_IN * sizeof(__half);   // 32 MB
    const bool   fp16_path = ws_size >= xh_bytes + 2048;

    // BN-stat replica count: as many 2KB replicas as the ws tail allows (<=64)
    const size_t tail = fp16_path ? (ws_size - xh_bytes) : ws_size;
    int rep = 1;
    while (rep < 64 && (size_t)(2 * rep) * 2 * C_OUT * sizeof(float) + 1024 <= tail)
        rep <<= 1;

    float* gsum = fp16_path ? (float*)((char*)d_ws + xh_bytes) : (float*)d_ws;
    float* ss   = gsum + (size_t)rep * 2 * C_OUT;

    sa_zero<<<1, 256, 0, stream>>>(gsum, rep * 2 * C_OUT);
    if (fp16_path) {
        __half* xh = (__half*)d_ws;
        const int n4 = N * C_IN / 4;
        sa_cvt   <<<2048, 256, 0, stream>>>((const float4*)x, (uint2*)xh, n4);
        sa_pool_h<<<M / 4, 256, 0, stream>>>(p, (const uint4*)xh, idx, knn, np_out, h);
    } else {
        sa_pool_f<<<M / 4, 256, 0, stream>>>(p, x, idx, knn, np_out, h);
    }
    sa_gemm    <<<M / 64, 256, 0, stream>>>(W, bias, h, gsum, (unsigned)(rep - 1));
    sa_finalize<<<1,      128, 0, stream>>>(gsum, gamma, beta, ss, no_out, M, rep);
    sa_bnrelu  <<<2048,   256, 0, stream>>>(h, ss, M);
}

// Round 6
// 130.715 us; speedup vs baseline: 1.1251x; 1.1251x over previous
//
#include <hip/hip_runtime.h>
#include <hip/hip_fp16.h>
#include <math.h>

#define K_NB  32
#define C_IN  64
#define C_OUT 128
#define KP    96     // packed pooled row: 64 x-max + 3 rel-xyz + 29 zeros (fp16)
#define TILE  128    // rows per gemm block; pooled fp16 packed tile-locally in h

typedef _Float16 f16x8 __attribute__((ext_vector_type(8)));
typedef float    f32x4 __attribute__((ext_vector_type(4)));

__device__ __forceinline__ float2 u2f2(unsigned u) {
    __half2 h = *reinterpret_cast<__half2*>(&u);
    return __half22float2(h);
}
__device__ __forceinline__ unsigned pk(float a, float b) {
    __half2 h = __floats2half2_rn(a, b);
    return *reinterpret_cast<unsigned*>(&h);
}

// ---------------------------------------------------------------------------
// zero n floats
// ---------------------------------------------------------------------------
__global__ __launch_bounds__(256) void sa_zero(float* __restrict__ g, int n)
{
    for (int i = threadIdx.x; i < n; i += 256) g[i] = 0.f;
}

// ---------------------------------------------------------------------------
// x (f32) -> fp16 copy in ws
// ---------------------------------------------------------------------------
__global__ __launch_bounds__(256) void sa_cvt(
    const float4* __restrict__ x4, uint2* __restrict__ xh, int n4)
{
    for (int i = blockIdx.x * blockDim.x + threadIdx.x; i < n4;
         i += gridDim.x * blockDim.x) {
        float4 v = x4[i];
        xh[i] = make_uint2(pk(v.x, v.y), pk(v.z, v.w));
    }
}

// ---------------------------------------------------------------------------
// pool: gather + max-pool; writes n_p (f32) and packed fp16 pooled row
// (96 halves) at tile-local offset inside the h region:
//   tile t = m>>7 owns h bytes [t*128*512, ...); row rl=m&127 at rl*192B.
// ---------------------------------------------------------------------------
__global__ __launch_bounds__(256) void sa_pool_h(
    const float* __restrict__ p, const uint4* __restrict__ xh4,
    const int* __restrict__ idx, const int* __restrict__ knn,
    float* __restrict__ np_out, float* __restrict__ hbuf)
{
    const int lane = threadIdx.x & 63;
    const int m    = blockIdx.x * 4 + (threadIdx.x >> 6);

    int kidx = 0;
    if (lane < K_NB) kidx = knn[m * K_NB + lane];

    float mx[8];
    #pragma unroll
    for (int j = 0; j < 8; ++j) mx[j] = -INFINITY;

    const int sub = lane & 7;            // 16B slice within the 128B fp16 row
    #pragma unroll
    for (int i = 0; i < 4; ++i) {
        int nb = __shfl(kidx, i * 8 + (lane >> 3));   // 8 rows in flight/inst
        uint4 u = xh4[(size_t)nb * 8 + sub];
        float2 f0 = u2f2(u.x), f1 = u2f2(u.y), f2 = u2f2(u.z), f3 = u2f2(u.w);
        mx[0] = fmaxf(mx[0], f0.x); mx[1] = fmaxf(mx[1], f0.y);
        mx[2] = fmaxf(mx[2], f1.x); mx[3] = fmaxf(mx[3], f1.y);
        mx[4] = fmaxf(mx[4], f2.x); mx[5] = fmaxf(mx[5], f2.y);
        mx[6] = fmaxf(mx[6], f3.x); mx[7] = fmaxf(mx[7], f3.y);
    }
    #pragma unroll
    for (int off = 8; off <= 32; off <<= 1)
        #pragma unroll
        for (int j = 0; j < 8; ++j)
            mx[j] = fmaxf(mx[j], __shfl_xor(mx[j], off));
    // now lanes 0..7 hold final maxes for channels lane*8+j

    float px = -INFINITY, py = -INFINITY, pz = -INFINITY;
    if (lane < K_NB) {
        const float* pp = p + (size_t)kidx * 3;
        px = pp[0]; py = pp[1]; pz = pp[2];
    }
    #pragma unroll
    for (int off = 32; off >= 1; off >>= 1) {
        px = fmaxf(px, __shfl_xor(px, off));
        py = fmaxf(py, __shfl_xor(py, off));
        pz = fmaxf(pz, __shfl_xor(pz, off));
    }

    const int s = idx[m];
    const float npx = p[(size_t)s*3+0];
    const float npy = p[(size_t)s*3+1];
    const float npz = p[(size_t)s*3+2];
    if (lane < 3) np_out[(size_t)m*3 + lane] = (lane == 0) ? npx : (lane == 1 ? npy : npz);

    const int tile = m >> 7, rl = m & (TILE - 1);
    __half* rowh = (__half*)(hbuf + (size_t)tile * TILE * C_OUT) + rl * KP;
    if (lane < 8) {
        *(uint4*)(rowh + lane * 8) =
            make_uint4(pk(mx[0],mx[1]), pk(mx[2],mx[3]), pk(mx[4],mx[5]), pk(mx[6],mx[7]));
    } else if (lane == 8) {
        *(uint4*)(rowh + 64) = make_uint4(pk(px-npx, py-npy), pk(pz-npz, 0.f), 0u, 0u);
    } else if (lane < 12) {
        *(uint4*)(rowh + 64 + (lane - 8) * 8) = make_uint4(0u, 0u, 0u, 0u);
    }
}

// f32-gather fallback (ws too small for fp16 x copy); same packed output
__global__ __launch_bounds__(256) void sa_pool_f(
    const float* __restrict__ p, const float* __restrict__ x,
    const int* __restrict__ idx, const int* __restrict__ knn,
    float* __restrict__ np_out, float* __restrict__ hbuf)
{
    const int lane = threadIdx.x & 63;
    const int m    = blockIdx.x * 4 + (threadIdx.x >> 6);
    int kidx = 0;
    if (lane < K_NB) kidx = knn[m * K_NB + lane];
    float xmax = -INFINITY;
    #pragma unroll
    for (int k = 0; k < K_NB; ++k) {
        int nb = __shfl(kidx, k);
        xmax = fmaxf(xmax, x[(size_t)nb * C_IN + lane]);
    }
    float px = -INFINITY, py = -INFINITY, pz = -INFINITY;
    if (lane < K_NB) {
        const float* pp = p + (size_t)kidx * 3;
        px = pp[0]; py = pp[1]; pz = pp[2];
    }
    #pragma unroll
    for (int off = 32; off >= 1; off >>= 1) {
        px = fmaxf(px, __shfl_xor(px, off));
        py = fmaxf(py, __shfl_xor(py, off));
        pz = fmaxf(pz, __shfl_xor(pz, off));
    }
    const int s = idx[m];
    const float npx = p[(size_t)s*3], npy = p[(size_t)s*3+1], npz = p[(size_t)s*3+2];
    if (lane < 3) np_out[(size_t)m*3 + lane] = (lane == 0) ? npx : (lane == 1 ? npy : npz);

    const int tile = m >> 7, rl = m & (TILE - 1);
    __half* rowh = (__half*)(hbuf + (size_t)tile * TILE * C_OUT) + rl * KP;
    if (lane < 8) {
        float v[8];
        #pragma unroll
        for (int j = 0; j < 8; ++j) v[j] = __shfl(xmax, lane * 8 + j);
        *(uint4*)(rowh + lane * 8) =
            make_uint4(pk(v[0],v[1]), pk(v[2],v[3]), pk(v[4],v[5]), pk(v[6],v[7]));
    } else if (lane == 8) {
        *(uint4*)(rowh + 64) = make_uint4(pk(px-npx, py-npy), pk(pz-npz, 0.f), 0u, 0u);
    } else if (lane < 12) {
        *(uint4*)(rowh + 64 + (lane - 8) * 8) = make_uint4(0u, 0u, 0u, 0u);
    }
}

// ---------------------------------------------------------------------------
// MFMA GEMM: h[tile rows, :] = pooled_fp16 @ Wt + b, fused BN partial stats.
// 128 rows x 128 cols per block, 4 waves; wave = 32 rows (2 row-tiles of 16);
// 8 col-tiles; K=96 = 3 steps of 32.  v_mfma_f32_16x16x32_f16:
//   A: row=lane&15, k=(lane>>4)*8+i ; B: col=lane&15, same k ;
//   D: col=lane&15, row=(lane>>4)*4+reg  (guide §3, m89-verified family)
// W staged in LDS as Wt[col][k] fp16, XOR-swizzled 16B chunks (bank spread).
// A-frags hoisted from global BEFORE barrier; stores after (alias-safe).
// ---------------------------------------------------------------------------
__global__ __launch_bounds__(256) void sa_gemm_mfma(
    const float* __restrict__ W, const float* __restrict__ bias,
    float* __restrict__ h, float* __restrict__ gsum, unsigned rep_mask)
{
    __shared__ __half Wt[C_OUT][128];    // 32 KB (12 of 16 chunks used, swizzled)
    __shared__ float reds[16][C_OUT];    // 8 KB
    __shared__ float redq[16][C_OUT];    // 8 KB

    const int t    = threadIdx.x;
    const int wave = t >> 6, lane = t & 63;
    const int l15  = lane & 15, lg = lane >> 4;
    const int m0   = blockIdx.x * TILE;

    // stage Wt[c][k]: k<64 -> W[3+k][c]; k<67 -> W[k-64][c]; else 0
    for (int e = t; e < C_OUT * KP; e += 256) {
        const int c = e & 127, kk = e >> 7;
        float w = 0.f;
        if (kk < C_IN)          w = W[(size_t)(3 + kk) * C_OUT + c];
        else if (kk < C_IN + 3) w = W[(size_t)(kk - C_IN) * C_OUT + c];
        Wt[c][(((kk >> 3) ^ (c & 7)) << 3) | (kk & 7)] = __float2half(w);
    }

    // hoist all A fragments (reads the fp16 region this block later overwrites)
    const __half* tb = (const __half*)(h + (size_t)blockIdx.x * TILE * C_OUT);
    f16x8 A[2][3];
    #pragma unroll
    for (int rt = 0; rt < 2; ++rt) {
        const int rl = wave * 32 + rt * 16 + l15;
        #pragma unroll
        for (int ks = 0; ks < 3; ++ks)
            A[rt][ks] = *(const f16x8*)(tb + (size_t)rl * KP + ks * 32 + lg * 8);
    }
    __syncthreads();   // Wt staged AND all A reads complete before any store

    f32x4 acc[2][8];
    #pragma unroll
    for (int ct = 0; ct < 8; ++ct) {
        const float bc = bias[ct * 16 + l15];
        acc[0][ct] = (f32x4){bc, bc, bc, bc};
        acc[1][ct] = (f32x4){bc, bc, bc, bc};
    }
    #pragma unroll
    for (int ks = 0; ks < 3; ++ks) {
        #pragma unroll
        for (int ct = 0; ct < 8; ++ct) {
            const int c  = ct * 16 + l15;
            const int kc = ks * 4 + lg;
            const f16x8 wf = *(const f16x8*)&Wt[c][((kc ^ (c & 7)) << 3)];
            acc[0][ct] = __builtin_amdgcn_mfma_f32_16x16x32_f16(A[0][ks], wf, acc[0][ct], 0, 0, 0);
            acc[1][ct] = __builtin_amdgcn_mfma_f32_16x16x32_f16(A[1][ks], wf, acc[1][ct], 0, 0, 0);
        }
    }

    // store + per-thread column stats
    float s8[8], q8[8];
    #pragma unroll
    for (int ct = 0; ct < 8; ++ct) { s8[ct] = 0.f; q8[ct] = 0.f; }
    #pragma unroll
    for (int rt = 0; rt < 2; ++rt) {
        #pragma unroll
        for (int ct = 0; ct < 8; ++ct) {
            const int col = ct * 16 + l15;
            #pragma unroll
            for (int r = 0; r < 4; ++r) {
                const int row = m0 + wave * 32 + rt * 16 + lg * 4 + r;
                const float v = acc[rt][ct][r];
                h[(size_t)row * C_OUT + col] = v;
                s8[ct] += v;
                q8[ct]  = fmaf(v, v, q8[ct]);
            }
        }
    }
    #pragma unroll
    for (int ct = 0; ct < 8; ++ct) {
        reds[wave * 4 + lg][ct * 16 + l15] = s8[ct];
        redq[wave * 4 + lg][ct * 16 + l15] = q8[ct];
    }
    __syncthreads();
    if (t < C_OUT) {
        float ss = 0.f, qq = 0.f;
        #pragma unroll
        for (int i = 0; i < 16; ++i) { ss += reds[i][t]; qq += redq[i][t]; }
        float* g = gsum + (size_t)(blockIdx.x & rep_mask) * 2 * C_OUT;
        atomicAdd(&g[t],         ss);
        atomicAdd(&g[C_OUT + t], qq);
    }
}

// ---------------------------------------------------------------------------
// sum replicas -> per-channel scale/shift; writes n_o
// ---------------------------------------------------------------------------
__global__ __launch_bounds__(128) void sa_finalize(
    const float* __restrict__ gsum, const float* __restrict__ gamma,
    const float* __restrict__ beta, float* __restrict__ ss,
    float* __restrict__ no_out, int M, int rep)
{
    const int j = threadIdx.x;
    float s = 0.f, s2 = 0.f;
    for (int r = 0; r < rep; ++r) {
        s  += gsum[(size_t)r * 2 * C_OUT + j];
        s2 += gsum[(size_t)r * 2 * C_OUT + C_OUT + j];
    }
    const float inv_m = 1.0f / (float)M;
    const float mean = s * inv_m;
    const float var  = fmaf(-mean, mean, s2 * inv_m);
    const float sc   = gamma[j] * rsqrtf(var + 1e-5f);
    ss[j]         = sc;
    ss[C_OUT + j] = fmaf(-mean, sc, beta[j]);
    if (j == 0) no_out[0] = (float)M;
}

// ---------------------------------------------------------------------------
// in-place affine + ReLU over h (float4)
// ---------------------------------------------------------------------------
__global__ __launch_bounds__(256) void sa_bnrelu(
    float* __restrict__ h, const float* __restrict__ ss, int M)
{
    __shared__ float sc[C_OUT], sh[C_OUT];
    if (threadIdx.x < C_OUT) {
        sc[threadIdx.x] = ss[threadIdx.x];
        sh[threadIdx.x] = ss[C_OUT + threadIdx.x];
    }
    __syncthreads();
    const size_t total4 = (size_t)M * C_OUT / 4;
    float4* h4 = (float4*)h;
    for (size_t i = (size_t)blockIdx.x * blockDim.x + threadIdx.x;
         i < total4; i += (size_t)gridDim.x * blockDim.x) {
        float4 v = h4[i];
        const int c = (int)((i * 4) & (C_OUT - 1));
        v.x = fmaxf(fmaf(v.x, sc[c+0], sh[c+0]), 0.f);
        v.y = fmaxf(fmaf(v.y, sc[c+1], sh[c+1]), 0.f);
        v.z = fmaxf(fmaf(v.z, sc[c+2], sh[c+2]), 0.f);
        v.w = fmaxf(fmaf(v.w, sc[c+3], sh[c+3]), 0.f);
        h4[i] = v;
    }
}

extern "C" void kernel_launch(void* const* d_in, const int* in_sizes, int n_in,
                              void* d_out, int out_size, void* d_ws, size_t ws_size,
                              hipStream_t stream)
{
    const float* p     = (const float*)d_in[0];
    const float* x     = (const float*)d_in[1];
    // d_in[2] = o (unused)
    const int*   idx   = (const int*)d_in[3];
    const int*   knn   = (const int*)d_in[4];
    const float* W     = (const float*)d_in[5];
    const float* bias  = (const float*)d_in[6];
    const float* gamma = (const float*)d_in[7];
    const float* beta  = (const float*)d_in[8];

    const int N = in_sizes[1] / C_IN;  // 262144
    const int M = in_sizes[3];         // 65536

    float* out    = (float*)d_out;
    float* np_out = out;                                     // [M,3]
    float* h      = out + (size_t)M * 3;                     // [M,128]
    float* no_out = out + (size_t)M * 3 + (size_t)M * C_OUT; // [1]

    const size_t xh_bytes  = (size_t)N * C_IN * sizeof(__half);   // 32 MB
    const bool   fp16_path = ws_size >= xh_bytes + 2048;

    const size_t tail = fp16_path ? (ws_size - xh_bytes) : ws_size;
    int rep = 1;
    while (rep < 64 && (size_t)(2 * rep) * 2 * C_OUT * sizeof(float) + 1024 <= tail)
        rep <<= 1;

    float* gsum = fp16_path ? (float*)((char*)d_ws + xh_bytes) : (float*)d_ws;
    float* ss   = gsum + (size_t)rep * 2 * C_OUT;

    sa_zero<<<1, 256, 0, stream>>>(gsum, rep * 2 * C_OUT);
    if (fp16_path) {
        __half* xh = (__half*)d_ws;
        const int n4 = N * C_IN / 4;
        sa_cvt   <<<2048, 256, 0, stream>>>((const float4*)x, (uint2*)xh, n4);
        sa_pool_h<<<M / 4, 256, 0, stream>>>(p, (const uint4*)xh, idx, knn, np_out, h);
    } else {
        sa_pool_f<<<M / 4, 256, 0, stream>>>(p, x, idx, knn, np_out, h);
    }
    sa_gemm_mfma<<<M / TILE, 256, 0, stream>>>(W, bias, h, gsum, (unsigned)(rep - 1));
    sa_finalize <<<1,        128, 0, stream>>>(gsum, gamma, beta, ss, no_out, M, rep);
    sa_bnrelu   <<<2048,     256, 0, stream>>>(h, ss, M);
}

// Round 9
// 112.219 us; speedup vs baseline: 1.3105x; 1.1648x over previous
//
#include <hip/hip_runtime.h>
#include <hip/hip_fp16.h>
#include <math.h>

#define K_NB   32
#define C_IN   64
#define C_OUT  128
#define KP     96     // packed pooled row: 64 x-max + 3 rel-xyz + 29 zeros (fp16)
#define TILE   128    // rows per gemm block
#define BN_EPS 1e-5f

typedef _Float16 f16x8 __attribute__((ext_vector_type(8)));
typedef float    f32x4 __attribute__((ext_vector_type(4)));

__device__ __forceinline__ unsigned pk(float a, float b) {
    __half2 h = __floats2half2_rn(a, b);
    return *reinterpret_cast<unsigned*>(&h);
}

// packed fp16 max on the 32-bit register view (v_pk_max_f16)
__device__ __forceinline__ unsigned pkmax(unsigned a, unsigned b) {
    unsigned d;
    asm volatile("v_pk_max_f16 %0, %1, %2" : "=v"(d) : "v"(a), "v"(b));
    return d;
}

// ---------------------------------------------------------------------------
// zero n floats (fallback path only)
// ---------------------------------------------------------------------------
__global__ __launch_bounds__(256) void sa_zero(float* __restrict__ g, int n)
{
    for (int i = threadIdx.x; i < n; i += 256) g[i] = 0.f;
}

// ---------------------------------------------------------------------------
// x (f32) -> fp16 copy in ws; block 0 also zeros the BN-stat replicas
// ---------------------------------------------------------------------------
__global__ __launch_bounds__(256) void sa_cvt(
    const float4* __restrict__ x4, uint2* __restrict__ xh, int n4,
    float* __restrict__ gsum, int ng)
{
    if (blockIdx.x == 0)
        for (int i = threadIdx.x; i < ng; i += 256) gsum[i] = 0.f;
    for (int i = blockIdx.x * blockDim.x + threadIdx.x; i < n4;
         i += gridDim.x * blockDim.x) {
        float4 v = x4[i];
        xh[i] = make_uint2(pk(v.x, v.y), pk(v.z, v.w));
    }
}

// ---------------------------------------------------------------------------
// pool: gather + max-pool fully in fp16 domain (v_pk_max_f16, no converts);
// writes n_p (f32) and the packed 96-half pooled row tile-locally in h region.
// ---------------------------------------------------------------------------
__global__ __launch_bounds__(256) void sa_pool_h(
    const float* __restrict__ p, const uint4* __restrict__ xh4,
    const int* __restrict__ idx, const int* __restrict__ knn,
    float* __restrict__ np_out, float* __restrict__ hbuf)
{
    const int lane = threadIdx.x & 63;
    const int m    = blockIdx.x * 4 + (threadIdx.x >> 6);

    int kidx = 0;
    if (lane < K_NB) kidx = knn[m * K_NB + lane];

    unsigned mx0 = 0xFC00FC00u, mx1 = 0xFC00FC00u;   // (-inf,-inf)
    unsigned mx2 = 0xFC00FC00u, mx3 = 0xFC00FC00u;

    const int sub = lane & 7;            // 16B slice within the 128B fp16 row
    #pragma unroll
    for (int i = 0; i < 4; ++i) {
        int nb = __shfl(kidx, i * 8 + (lane >> 3));      // 8 rows in flight/inst
        uint4 u = xh4[(size_t)nb * 8 + sub];
        mx0 = pkmax(mx0, u.x);
        mx1 = pkmax(mx1, u.y);
        mx2 = pkmax(mx2, u.z);
        mx3 = pkmax(mx3, u.w);
    }
    // butterfly over lane bits 3,4,5 (row-group merge), fp16 packed max
    #pragma unroll
    for (int off = 8; off <= 32; off <<= 1) {
        mx0 = pkmax(mx0, (unsigned)__shfl_xor((int)mx0, off));
        mx1 = pkmax(mx1, (unsigned)__shfl_xor((int)mx1, off));
        mx2 = pkmax(mx2, (unsigned)__shfl_xor((int)mx2, off));
        mx3 = pkmax(mx3, (unsigned)__shfl_xor((int)mx3, off));
    }

    // xyz max-pool (fp32 p, L2-resident)
    float px = -INFINITY, py = -INFINITY, pz = -INFINITY;
    if (lane < K_NB) {
        const float* pp = p + (size_t)kidx * 3;
        px = pp[0]; py = pp[1]; pz = pp[2];
    }
    #pragma unroll
    for (int off = 32; off >= 1; off >>= 1) {
        px = fmaxf(px, __shfl_xor(px, off));
        py = fmaxf(py, __shfl_xor(py, off));
        pz = fmaxf(pz, __shfl_xor(pz, off));
    }

    const int s = idx[m];
    const float npx = p[(size_t)s*3+0];
    const float npy = p[(size_t)s*3+1];
    const float npz = p[(size_t)s*3+2];
    if (lane < 3) np_out[(size_t)m*3 + lane] = (lane == 0) ? npx : (lane == 1 ? npy : npz);

    const int tile = m >> 7, rl = m & (TILE - 1);
    __half* rowh = (__half*)(hbuf + (size_t)tile * TILE * C_OUT) + rl * KP;
    if (lane < 8) {
        *(uint4*)(rowh + lane * 8) = make_uint4(mx0, mx1, mx2, mx3);
    } else if (lane == 8) {
        *(uint4*)(rowh + 64) = make_uint4(pk(px-npx, py-npy), pk(pz-npz, 0.f), 0u, 0u);
    } else if (lane < 12) {
        *(uint4*)(rowh + 64 + (lane - 8) * 8) = make_uint4(0u, 0u, 0u, 0u);
    }
}

// f32-gather fallback (ws too small for fp16 x copy); same packed output
__global__ __launch_bounds__(256) void sa_pool_f(
    const float* __restrict__ p, const float* __restrict__ x,
    const int* __restrict__ idx, const int* __restrict__ knn,
    float* __restrict__ np_out, float* __restrict__ hbuf)
{
    const int lane = threadIdx.x & 63;
    const int m    = blockIdx.x * 4 + (threadIdx.x >> 6);
    int kidx = 0;
    if (lane < K_NB) kidx = knn[m * K_NB + lane];
    float xmax = -INFINITY;
    #pragma unroll
    for (int k = 0; k < K_NB; ++k) {
        int nb = __shfl(kidx, k);
        xmax = fmaxf(xmax, x[(size_t)nb * C_IN + lane]);
    }
    float px = -INFINITY, py = -INFINITY, pz = -INFINITY;
    if (lane < K_NB) {
        const float* pp = p + (size_t)kidx * 3;
        px = pp[0]; py = pp[1]; pz = pp[2];
    }
    #pragma unroll
    for (int off = 32; off >= 1; off >>= 1) {
        px = fmaxf(px, __shfl_xor(px, off));
        py = fmaxf(py, __shfl_xor(py, off));
        pz = fmaxf(pz, __shfl_xor(pz, off));
    }
    const int s = idx[m];
    const float npx = p[(size_t)s*3], npy = p[(size_t)s*3+1], npz = p[(size_t)s*3+2];
    if (lane < 3) np_out[(size_t)m*3 + lane] = (lane == 0) ? npx : (lane == 1 ? npy : npz);

    const int tile = m >> 7, rl = m & (TILE - 1);
    __half* rowh = (__half*)(hbuf + (size_t)tile * TILE * C_OUT) + rl * KP;
    if (lane < 8) {
        float v[8];
        #pragma unroll
        for (int j = 0; j < 8; ++j) v[j] = __shfl(xmax, lane * 8 + j);
        *(uint4*)(rowh + lane * 8) =
            make_uint4(pk(v[0],v[1]), pk(v[2],v[3]), pk(v[4],v[5]), pk(v[6],v[7]));
    } else if (lane == 8) {
        *(uint4*)(rowh + 64) = make_uint4(pk(px-npx, py-npy), pk(pz-npz, 0.f), 0u, 0u);
    } else if (lane < 12) {
        *(uint4*)(rowh + 64 + (lane - 8) * 8) = make_uint4(0u, 0u, 0u, 0u);
    }
}

// ---------------------------------------------------------------------------
// MFMA GEMM (R6-proven): h[tile,:] = pooled_fp16 @ Wt + b, raw store, fused
// BN partial stats -> replicated gsum atomics.
// ---------------------------------------------------------------------------
__global__ __launch_bounds__(256) void sa_gemm_mfma(
    const float* __restrict__ W, const float* __restrict__ bias,
    float* __restrict__ h, float* __restrict__ gsum, unsigned rep_mask)
{
    __shared__ __half Wt[C_OUT][128];    // 32 KB (12/16 chunks used, swizzled)
    __shared__ float reds[16][C_OUT];    // 8 KB
    __shared__ float redq[16][C_OUT];    // 8 KB

    const int t    = threadIdx.x;
    const int wave = t >> 6, lane = t & 63;
    const int l15  = lane & 15, lg = lane >> 4;
    const int m0   = blockIdx.x * TILE;

    // stage Wt[c][k]: k<64 -> W[3+k][c]; k<67 -> W[k-64][c]; else 0
    for (int e = t; e < C_OUT * KP; e += 256) {
        const int c = e & 127, kk = e >> 7;
        float w = 0.f;
        if (kk < C_IN)          w = W[(size_t)(3 + kk) * C_OUT + c];
        else if (kk < C_IN + 3) w = W[(size_t)(kk - C_IN) * C_OUT + c];
        Wt[c][(((kk >> 3) ^ (c & 7)) << 3) | (kk & 7)] = __float2half(w);
    }

    // hoist all A fragments (fp16 region this block later overwrites)
    const __half* tb = (const __half*)(h + (size_t)blockIdx.x * TILE * C_OUT);
    f16x8 A[2][3];
    #pragma unroll
    for (int rt = 0; rt < 2; ++rt) {
        const int rl = wave * 32 + rt * 16 + l15;
        #pragma unroll
        for (int ks = 0; ks < 3; ++ks)
            A[rt][ks] = *(const f16x8*)(tb + (size_t)rl * KP + ks * 32 + lg * 8);
    }
    __syncthreads();   // Wt staged AND all A reads complete before any store

    f32x4 acc[2][8];
    #pragma unroll
    for (int ct = 0; ct < 8; ++ct) {
        const float bc = bias[ct * 16 + l15];
        acc[0][ct] = (f32x4){bc, bc, bc, bc};
        acc[1][ct] = (f32x4){bc, bc, bc, bc};
    }
    #pragma unroll
    for (int ks = 0; ks < 3; ++ks) {
        #pragma unroll
        for (int ct = 0; ct < 8; ++ct) {
            const int c  = ct * 16 + l15;
            const int kc = ks * 4 + lg;
            const f16x8 wf = *(const f16x8*)&Wt[c][((kc ^ (c & 7)) << 3)];
            acc[0][ct] = __builtin_amdgcn_mfma_f32_16x16x32_f16(A[0][ks], wf, acc[0][ct], 0, 0, 0);
            acc[1][ct] = __builtin_amdgcn_mfma_f32_16x16x32_f16(A[1][ks], wf, acc[1][ct], 0, 0, 0);
        }
    }

    // store raw h + per-thread column stats
    float s8[8], q8[8];
    #pragma unroll
    for (int ct = 0; ct < 8; ++ct) { s8[ct] = 0.f; q8[ct] = 0.f; }
    #pragma unroll
    for (int rt = 0; rt < 2; ++rt) {
        #pragma unroll
        for (int ct = 0; ct < 8; ++ct) {
            const int col = ct * 16 + l15;
            #pragma unroll
            for (int r = 0; r < 4; ++r) {
                const int row = m0 + wave * 32 + rt * 16 + lg * 4 + r;
                const float v = acc[rt][ct][r];
                h[(size_t)row * C_OUT + col] = v;
                s8[ct] += v;
                q8[ct]  = fmaf(v, v, q8[ct]);
            }
        }
    }
    #pragma unroll
    for (int ct = 0; ct < 8; ++ct) {
        reds[wave * 4 + lg][ct * 16 + l15] = s8[ct];
        redq[wave * 4 + lg][ct * 16 + l15] = q8[ct];
    }
    __syncthreads();
    if (t < C_OUT) {
        float ss = 0.f, qq = 0.f;
        #pragma unroll
        for (int i = 0; i < 16; ++i) { ss += reds[i][t]; qq += redq[i][t]; }
        float* g = gsum + (size_t)(blockIdx.x & rep_mask) * 2 * C_OUT;
        atomicAdd(&g[t],         ss);
        atomicAdd(&g[C_OUT + t], qq);
    }
}

// ---------------------------------------------------------------------------
// finalize fused into BN+ReLU: every block reduces the rep replicas (tiny),
// computes scale/shift in LDS, then grid-strides the in-place affine.
// Block 0 writes n_o.
// ---------------------------------------------------------------------------
__global__ __launch_bounds__(256) void sa_bnrelu_fin(
    float* __restrict__ h, const float* __restrict__ gsum,
    const float* __restrict__ gamma, const float* __restrict__ beta,
    float* __restrict__ no_out, int M, int rep)
{
    __shared__ float sc[C_OUT], sh[C_OUT];
    const int t = threadIdx.x;
    if (t < C_OUT) {
        float s = 0.f, s2 = 0.f;
        for (int r = 0; r < rep; ++r) {
            s  += gsum[(size_t)r * 2 * C_OUT + t];
            s2 += gsum[(size_t)r * 2 * C_OUT + C_OUT + t];
        }
        const float inv_m = 1.0f / (float)M;
        const float mean = s * inv_m;
        const float var  = fmaf(-mean, mean, s2 * inv_m);
        const float scv  = gamma[t] * rsqrtf(var + BN_EPS);
        sc[t] = scv;
        sh[t] = fmaf(-mean, scv, beta[t]);
    }
    if (blockIdx.x == 0 && t == 0) no_out[0] = (float)M;
    __syncthreads();

    const size_t total4 = (size_t)M * C_OUT / 4;
    float4* h4 = (float4*)h;
    for (size_t i = (size_t)blockIdx.x * blockDim.x + t;
         i < total4; i += (size_t)gridDim.x * blockDim.x) {
        float4 v = h4[i];
        const int c = (int)((i * 4) & (C_OUT - 1));
        v.x = fmaxf(fmaf(v.x, sc[c+0], sh[c+0]), 0.f);
        v.y = fmaxf(fmaf(v.y, sc[c+1], sh[c+1]), 0.f);
        v.z = fmaxf(fmaf(v.z, sc[c+2], sh[c+2]), 0.f);
        v.w = fmaxf(fmaf(v.w, sc[c+3], sh[c+3]), 0.f);
        h4[i] = v;
    }
}

extern "C" void kernel_launch(void* const* d_in, const int* in_sizes, int n_in,
                              void* d_out, int out_size, void* d_ws, size_t ws_size,
                              hipStream_t stream)
{
    const float* p     = (const float*)d_in[0];
    const float* x     = (const float*)d_in[1];
    // d_in[2] = o (unused)
    const int*   idx   = (const int*)d_in[3];
    const int*   knn   = (const int*)d_in[4];
    const float* W     = (const float*)d_in[5];
    const float* bias  = (const float*)d_in[6];
    const float* gamma = (const float*)d_in[7];
    const float* beta  = (const float*)d_in[8];

    const int N = in_sizes[1] / C_IN;  // 262144
    const int M = in_sizes[3];         // 65536

    float* out    = (float*)d_out;
    float* np_out = out;                                     // [M,3]
    float* h      = out + (size_t)M * 3;                     // [M,128]
    float* no_out = out + (size_t)M * 3 + (size_t)M * C_OUT; // [1]

    const size_t xh_bytes  = (size_t)N * C_IN * sizeof(__half);   // 32 MB
    const bool   fp16_path = ws_size >= xh_bytes + 2048;

    const size_t tail = fp16_path ? (ws_size - xh_bytes) : ws_size;
    int rep = 1;
    while (rep < 8 && (size_t)(2 * rep) * 2 * C_OUT * sizeof(float) <= tail)
        rep <<= 1;

    float* gsum = fp16_path ? (float*)((char*)d_ws + xh_bytes) : (float*)d_ws;
    const unsigned rep_mask = (unsigned)(rep - 1);

    if (fp16_path) {
        __half* xh = (__half*)d_ws;
        const int n4 = N * C_IN / 4;
        sa_cvt   <<<2048, 256, 0, stream>>>((const float4*)x, (uint2*)xh, n4,
                                            gsum, rep * 2 * C_OUT);
        sa_pool_h<<<M / 4, 256, 0, stream>>>(p, (const uint4*)xh, idx, knn, np_out, h);
    } else {
        sa_zero  <<<1, 256, 0, stream>>>(gsum, rep * 2 * C_OUT);
        sa_pool_f<<<M / 4, 256, 0, stream>>>(p, x, idx, knn, np_out, h);
    }

    sa_gemm_mfma <<<M / TILE, 256, 0, stream>>>(W, bias, h, gsum, rep_mask);
    sa_bnrelu_fin<<<1024,     256, 0, stream>>>(h, gsum, gamma, beta, no_out, M, rep);
}

// Round 11
// 108.042 us; speedup vs baseline: 1.3611x; 1.0387x over previous
//
#include <hip/hip_runtime.h>
#include <hip/hip_fp16.h>
#include <math.h>

#define K_NB   32
#define C_IN   64
#define C_OUT  128
#define KP     96     // packed pooled row: 64 x-max + 3 rel-xyz + 29 zeros (fp16)
#define TILE   128    // rows per gemm block
#define BN_EPS 1e-5f

typedef _Float16 f16x8 __attribute__((ext_vector_type(8)));
typedef float    f32x4 __attribute__((ext_vector_type(4)));
typedef float    f32x2 __attribute__((ext_vector_type(2)));

__device__ __forceinline__ unsigned pk(float a, float b) {
    __half2 h = __floats2half2_rn(a, b);
    return *reinterpret_cast<unsigned*>(&h);
}

// packed fp16 max on the 32-bit register view (v_pk_max_f16)
__device__ __forceinline__ unsigned pkmax(unsigned a, unsigned b) {
    unsigned d;
    asm volatile("v_pk_max_f16 %0, %1, %2" : "=v"(d) : "v"(a), "v"(b));
    return d;
}

// bit-view of cvt_pkrtz result (its return type is an __fp16 ext-vector)
using pkrtz_t = decltype(__builtin_amdgcn_cvt_pkrtz(0.f, 0.f));
__device__ __forceinline__ unsigned h2u(pkrtz_t v) {
    union { pkrtz_t h; unsigned u; } c; c.h = v; return c.u;
}

// decode one dword of 4 fp8 (e4m3) -> two packed-fp16 dwords (exact)
__device__ __forceinline__ void fp8x4_to_h2x2(unsigned d, unsigned& lo, unsigned& hi) {
    f32x2 a = __builtin_amdgcn_cvt_pk_f32_fp8((int)d, false);
    f32x2 b = __builtin_amdgcn_cvt_pk_f32_fp8((int)d, true);
    lo = h2u(__builtin_amdgcn_cvt_pkrtz(a.x, a.y));
    hi = h2u(__builtin_amdgcn_cvt_pkrtz(b.x, b.y));
}

// ---------------------------------------------------------------------------
// zero n floats (fallback path only)
// ---------------------------------------------------------------------------
__global__ __launch_bounds__(256) void sa_zero(float* __restrict__ g, int n)
{
    for (int i = threadIdx.x; i < n; i += 256) g[i] = 0.f;
}

// ---------------------------------------------------------------------------
// x (f32) -> fp8 e4m3 copy in ws (16 B out per 64 B in, per thread);
// block 0 also zeros the BN-stat replicas
// ---------------------------------------------------------------------------
__global__ __launch_bounds__(256) void sa_cvt(
    const float4* __restrict__ x4, uint4* __restrict__ xq, int n16,
    float* __restrict__ gsum, int ng)
{
    if (blockIdx.x == 0)
        for (int i = threadIdx.x; i < ng; i += 256) gsum[i] = 0.f;
    for (int i = blockIdx.x * blockDim.x + threadIdx.x; i < n16;
         i += gridDim.x * blockDim.x) {
        float4 v0 = x4[4*i+0], v1 = x4[4*i+1], v2 = x4[4*i+2], v3 = x4[4*i+3];
        int w0 = 0, w1 = 0, w2 = 0, w3 = 0;
        w0 = __builtin_amdgcn_cvt_pk_fp8_f32(v0.x, v0.y, w0, false);
        w0 = __builtin_amdgcn_cvt_pk_fp8_f32(v0.z, v0.w, w0, true);
        w1 = __builtin_amdgcn_cvt_pk_fp8_f32(v1.x, v1.y, w1, false);
        w1 = __builtin_amdgcn_cvt_pk_fp8_f32(v1.z, v1.w, w1, true);
        w2 = __builtin_amdgcn_cvt_pk_fp8_f32(v2.x, v2.y, w2, false);
        w2 = __builtin_amdgcn_cvt_pk_fp8_f32(v2.z, v2.w, w2, true);
        w3 = __builtin_amdgcn_cvt_pk_fp8_f32(v3.x, v3.y, w3, false);
        w3 = __builtin_amdgcn_cvt_pk_fp8_f32(v3.z, v3.w, w3, true);
        xq[i] = make_uint4((unsigned)w0, (unsigned)w1, (unsigned)w2, (unsigned)w3);
    }
}

// ---------------------------------------------------------------------------
// pool: fp8 gather (64 B rows, 8 lanes x uint2 per row, 4 iterations),
// decode fp8->fp16 (exact), packed-fp16 max; writes n_p (f32) and the packed
// 96-half pooled row tile-locally in the h region.
// ---------------------------------------------------------------------------
__global__ __launch_bounds__(256) void sa_pool_h(
    const float* __restrict__ p, const uint2* __restrict__ xq2,
    const int* __restrict__ idx, const int* __restrict__ knn,
    float* __restrict__ np_out, float* __restrict__ hbuf)
{
    const int lane = threadIdx.x & 63;
    const int m    = blockIdx.x * 4 + (threadIdx.x >> 6);

    int kidx = 0;
    if (lane < K_NB) kidx = knn[m * K_NB + lane];

    unsigned mx0 = 0xFC00FC00u, mx1 = 0xFC00FC00u;   // (-inf,-inf) fp16
    unsigned mx2 = 0xFC00FC00u, mx3 = 0xFC00FC00u;

    const int sub = lane & 7;            // 8B slice within the 64B fp8 row
    #pragma unroll
    for (int i = 0; i < 4; ++i) {
        int nb = __shfl(kidx, i * 8 + (lane >> 3));      // 8 rows in flight/inst
        uint2 u = xq2[(size_t)nb * 8 + sub];
        unsigned h01, h23, h45, h67;
        fp8x4_to_h2x2(u.x, h01, h23);
        fp8x4_to_h2x2(u.y, h45, h67);
        mx0 = pkmax(mx0, h01);
        mx1 = pkmax(mx1, h23);
        mx2 = pkmax(mx2, h45);
        mx3 = pkmax(mx3, h67);
    }
    // butterfly over lane bits 3,4,5 (row-group merge), fp16 packed max
    #pragma unroll
    for (int off = 8; off <= 32; off <<= 1) {
        mx0 = pkmax(mx0, (unsigned)__shfl_xor((int)mx0, off));
        mx1 = pkmax(mx1, (unsigned)__shfl_xor((int)mx1, off));
        mx2 = pkmax(mx2, (unsigned)__shfl_xor((int)mx2, off));
        mx3 = pkmax(mx3, (unsigned)__shfl_xor((int)mx3, off));
    }

    // xyz max-pool (fp32 p, L2-resident)
    float px = -INFINITY, py = -INFINITY, pz = -INFINITY;
    if (lane < K_NB) {
        const float* pp = p + (size_t)kidx * 3;
        px = pp[0]; py = pp[1]; pz = pp[2];
    }
    #pragma unroll
    for (int off = 32; off >= 1; off >>= 1) {
        px = fmaxf(px, __shfl_xor(px, off));
        py = fmaxf(py, __shfl_xor(py, off));
        pz = fmaxf(pz, __shfl_xor(pz, off));
    }

    const int s = idx[m];
    const float npx = p[(size_t)s*3+0];
    const float npy = p[(size_t)s*3+1];
    const float npz = p[(size_t)s*3+2];
    if (lane < 3) np_out[(size_t)m*3 + lane] = (lane == 0) ? npx : (lane == 1 ? npy : npz);

    const int tile = m >> 7, rl = m & (TILE - 1);
    __half* rowh = (__half*)(hbuf + (size_t)tile * TILE * C_OUT) + rl * KP;
    if (lane < 8) {
        *(uint4*)(rowh + lane * 8) = make_uint4(mx0, mx1, mx2, mx3);
    } else if (lane == 8) {
        *(uint4*)(rowh + 64) = make_uint4(pk(px-npx, py-npy), pk(pz-npz, 0.f), 0u, 0u);
    } else if (lane < 12) {
        *(uint4*)(rowh + 64 + (lane - 8) * 8) = make_uint4(0u, 0u, 0u, 0u);
    }
}

// f32-gather fallback (ws too small for fp8 x copy); same packed output
__global__ __launch_bounds__(256) void sa_pool_f(
    const float* __restrict__ p, const float* __restrict__ x,
    const int* __restrict__ idx, const int* __restrict__ knn,
    float* __restrict__ np_out, float* __restrict__ hbuf)
{
    const int lane = threadIdx.x & 63;
    const int m    = blockIdx.x * 4 + (threadIdx.x >> 6);
    int kidx = 0;
    if (lane < K_NB) kidx = knn[m * K_NB + lane];
    float xmax = -INFINITY;
    #pragma unroll
    for (int k = 0; k < K_NB; ++k) {
        int nb = __shfl(kidx, k);
        xmax = fmaxf(xmax, x[(size_t)nb * C_IN + lane]);
    }
    float px = -INFINITY, py = -INFINITY, pz = -INFINITY;
    if (lane < K_NB) {
        const float* pp = p + (size_t)kidx * 3;
        px = pp[0]; py = pp[1]; pz = pp[2];
    }
    #pragma unroll
    for (int off = 32; off >= 1; off >>= 1) {
        px = fmaxf(px, __shfl_xor(px, off));
        py = fmaxf(py, __shfl_xor(py, off));
        pz = fmaxf(pz, __shfl_xor(pz, off));
    }
    const int s = idx[m];
    const float npx = p[(size_t)s*3], npy = p[(size_t)s*3+1], npz = p[(size_t)s*3+2];
    if (lane < 3) np_out[(size_t)m*3 + lane] = (lane == 0) ? npx : (lane == 1 ? npy : npz);

    const int tile = m >> 7, rl = m & (TILE - 1);
    __half* rowh = (__half*)(hbuf + (size_t)tile * TILE * C_OUT) + rl * KP;
    if (lane < 8) {
        float v[8];
        #pragma unroll
        for (int j = 0; j < 8; ++j) v[j] = __shfl(xmax, lane * 8 + j);
        *(uint4*)(rowh + lane * 8) =
            make_uint4(pk(v[0],v[1]), pk(v[2],v[3]), pk(v[4],v[5]), pk(v[6],v[7]));
    } else if (lane == 8) {
        *(uint4*)(rowh + 64) = make_uint4(pk(px-npx, py-npy), pk(pz-npz, 0.f), 0u, 0u);
    } else if (lane < 12) {
        *(uint4*)(rowh + 64 + (lane - 8) * 8) = make_uint4(0u, 0u, 0u, 0u);
    }
}

// ---------------------------------------------------------------------------
// MFMA GEMM (R6/R9-proven): h[tile,:] = pooled_fp16 @ Wt + b, raw store,
// fused BN partial stats -> replicated gsum atomics.
// ---------------------------------------------------------------------------
__global__ __launch_bounds__(256) void sa_gemm_mfma(
    const float* __restrict__ W, const float* __restrict__ bias,
    float* __restrict__ h, float* __restrict__ gsum, unsigned rep_mask)
{
    __shared__ __half Wt[C_OUT][128];    // 32 KB (12/16 chunks used, swizzled)
    __shared__ float reds[16][C_OUT];    // 8 KB
    __shared__ float redq[16][C_OUT];    // 8 KB

    const int t    = threadIdx.x;
    const int wave = t >> 6, lane = t & 63;
    const int l15  = lane & 15, lg = lane >> 4;
    const int m0   = blockIdx.x * TILE;

    // stage Wt[c][k]: k<64 -> W[3+k][c]; k<67 -> W[k-64][c]; else 0
    for (int e = t; e < C_OUT * KP; e += 256) {
        const int c = e & 127, kk = e >> 7;
        float w = 0.f;
        if (kk < C_IN)          w = W[(size_t)(3 + kk) * C_OUT + c];
        else if (kk < C_IN + 3) w = W[(size_t)(kk - C_IN) * C_OUT + c];
        Wt[c][(((kk >> 3) ^ (c & 7)) << 3) | (kk & 7)] = __float2half(w);
    }

    // hoist all A fragments (fp16 region this block later overwrites)
    const __half* tb = (const __half*)(h + (size_t)blockIdx.x * TILE * C_OUT);
    f16x8 A[2][3];
    #pragma unroll
    for (int rt = 0; rt < 2; ++rt) {
        const int rl = wave * 32 + rt * 16 + l15;
        #pragma unroll
        for (int ks = 0; ks < 3; ++ks)
            A[rt][ks] = *(const f16x8*)(tb + (size_t)rl * KP + ks * 32 + lg * 8);
    }
    __syncthreads();   // Wt staged AND all A reads complete before any store

    f32x4 acc[2][8];
    #pragma unroll
    for (int ct = 0; ct < 8; ++ct) {
        const float bc = bias[ct * 16 + l15];
        acc[0][ct] = (f32x4){bc, bc, bc, bc};
        acc[1][ct] = (f32x4){bc, bc, bc, bc};
    }
    #pragma unroll
    for (int ks = 0; ks < 3; ++ks) {
        #pragma unroll
        for (int ct = 0; ct < 8; ++ct) {
            const int c  = ct * 16 + l15;
            const int kc = ks * 4 + lg;
            const f16x8 wf = *(const f16x8*)&Wt[c][((kc ^ (c & 7)) << 3)];
            acc[0][ct] = __builtin_amdgcn_mfma_f32_16x16x32_f16(A[0][ks], wf, acc[0][ct], 0, 0, 0);
            acc[1][ct] = __builtin_amdgcn_mfma_f32_16x16x32_f16(A[1][ks], wf, acc[1][ct], 0, 0, 0);
        }
    }

    // store raw h + per-thread column stats
    float s8[8], q8[8];
    #pragma unroll
    for (int ct = 0; ct < 8; ++ct) { s8[ct] = 0.f; q8[ct] = 0.f; }
    #pragma unroll
    for (int rt = 0; rt < 2; ++rt) {
        #pragma unroll
        for (int ct = 0; ct < 8; ++ct) {
            const int col = ct * 16 + l15;
            #pragma unroll
            for (int r = 0; r < 4; ++r) {
                const int row = m0 + wave * 32 + rt * 16 + lg * 4 + r;
                const float v = acc[rt][ct][r];
                h[(size_t)row * C_OUT + col] = v;
                s8[ct] += v;
                q8[ct]  = fmaf(v, v, q8[ct]);
            }
        }
    }
    #pragma unroll
    for (int ct = 0; ct < 8; ++ct) {
        reds[wave * 4 + lg][ct * 16 + l15] = s8[ct];
        redq[wave * 4 + lg][ct * 16 + l15] = q8[ct];
    }
    __syncthreads();
    if (t < C_OUT) {
        float ss = 0.f, qq = 0.f;
        #pragma unroll
        for (int i = 0; i < 16; ++i) { ss += reds[i][t]; qq += redq[i][t]; }
        float* g = gsum + (size_t)(blockIdx.x & rep_mask) * 2 * C_OUT;
        atomicAdd(&g[t],         ss);
        atomicAdd(&g[C_OUT + t], qq);
    }
}

// ---------------------------------------------------------------------------
// finalize fused into BN+ReLU: every block reduces the rep replicas (tiny),
// computes scale/shift in LDS, then grid-strides the in-place affine.
// Block 0 writes n_o.
// ---------------------------------------------------------------------------
__global__ __launch_bounds__(256) void sa_bnrelu_fin(
    float* __restrict__ h, const float* __restrict__ gsum,
    const float* __restrict__ gamma, const float* __restrict__ beta,
    float* __restrict__ no_out, int M, int rep)
{
    __shared__ float sc[C_OUT], sh[C_OUT];
    const int t = threadIdx.x;
    if (t < C_OUT) {
        float s = 0.f, s2 = 0.f;
        for (int r = 0; r < rep; ++r) {
            s  += gsum[(size_t)r * 2 * C_OUT + t];
            s2 += gsum[(size_t)r * 2 * C_OUT + C_OUT + t];
        }
        const float inv_m = 1.0f / (float)M;
        const float mean = s * inv_m;
        const float var  = fmaf(-mean, mean, s2 * inv_m);
        const float scv  = gamma[t] * rsqrtf(var + BN_EPS);
        sc[t] = scv;
        sh[t] = fmaf(-mean, scv, beta[t]);
    }
    if (blockIdx.x == 0 && t == 0) no_out[0] = (float)M;
    __syncthreads();

    const size_t total4 = (size_t)M * C_OUT / 4;
    float4* h4 = (float4*)h;
    for (size_t i = (size_t)blockIdx.x * blockDim.x + t;
         i < total4; i += (size_t)gridDim.x * blockDim.x) {
        float4 v = h4[i];
        const int c = (int)((i * 4) & (C_OUT - 1));
        v.x = fmaxf(fmaf(v.x, sc[c+0], sh[c+0]), 0.f);
        v.y = fmaxf(fmaf(v.y, sc[c+1], sh[c+1]), 0.f);
        v.z = fmaxf(fmaf(v.z, sc[c+2], sh[c+2]), 0.f);
        v.w = fmaxf(fmaf(v.w, sc[c+3], sh[c+3]), 0.f);
        h4[i] = v;
    }
}

extern "C" void kernel_launch(void* const* d_in, const int* in_sizes, int n_in,
                              void* d_out, int out_size, void* d_ws, size_t ws_size,
                              hipStream_t stream)
{
    const float* p     = (const float*)d_in[0];
    const float* x     = (const float*)d_in[1];
    // d_in[2] = o (unused)
    const int*   idx   = (const int*)d_in[3];
    const int*   knn   = (const int*)d_in[4];
    const float* W     = (const float*)d_in[5];
    const float* bias  = (const float*)d_in[6];
    const float* gamma = (const float*)d_in[7];
    const float* beta  = (const float*)d_in[8];

    const int N = in_sizes[1] / C_IN;  // 262144
    const int M = in_sizes[3];         // 65536

    float* out    = (float*)d_out;
    float* np_out = out;                                     // [M,3]
    float* h      = out + (size_t)M * 3;                     // [M,128]
    float* no_out = out + (size_t)M * 3 + (size_t)M * C_OUT; // [1]

    const size_t xq_bytes = (size_t)N * C_IN;                // 16 MB fp8 table
    const bool   fp8_path = ws_size >= xq_bytes + 2048;

    const size_t tail = fp8_path ? (ws_size - xq_bytes) : ws_size;
    int rep = 1;
    while (rep < 8 && (size_t)(2 * rep) * 2 * C_OUT * sizeof(float) <= tail)
        rep <<= 1;

    float* gsum = fp8_path ? (float*)((char*)d_ws + xq_bytes) : (float*)d_ws;
    const unsigned rep_mask = (unsigned)(rep - 1);

    if (fp8_path) {
        uint4* xq = (uint4*)d_ws;
        const int n16 = N * C_IN / 16;
        sa_cvt   <<<2048, 256, 0, stream>>>((const float4*)x, xq, n16,
                                            gsum, rep * 2 * C_OUT);
        sa_pool_h<<<M / 4, 256, 0, stream>>>(p, (const uint2*)d_ws, idx, knn, np_out, h);
    } else {
        sa_zero  <<<1, 256, 0, stream>>>(gsum, rep * 2 * C_OUT);
        sa_pool_f<<<M / 4, 256, 0, stream>>>(p, x, idx, knn, np_out, h);
    }

    sa_gemm_mfma <<<M / TILE, 256, 0, stream>>>(W, bias, h, gsum, rep_mask);
    sa_bnrelu_fin<<<1024,     256, 0, stream>>>(h, gsum, gamma, beta, no_out, M, rep);
}